// Round 25
// baseline (20.119 us; speedup 1.0000x reference)
//
#include <hip/hip_runtime.h>

#define KS    7
#define RAD   3
#define TW    32            // tile width (output px)
#define TH    16            // tile height (256 thr x 2px: 1 block/CU)
#define HR    22            // halo rows = TH + 2*RAD
#define PAIRS 21            // col-pairs per parity row (19 needed, +2 pad)
#define NSITE (HR*2*PAIRS)  // 924 sites
#define H     256
#define W     256
#define HWp   (H*W)
#define NTASK2 (HR*10*2)    // 440 staging tasks/group: (row, quad, ch-quad)

typedef __fp16    h2raw __attribute__((ext_vector_type(2)));
typedef _Float16  f16x2 __attribute__((ext_vector_type(2)));

__device__ __forceinline__ unsigned pk(float a, float b) {
    h2raw h = __builtin_amdgcn_cvt_pkrtz(a, b);
    return __builtin_bit_cast(unsigned, h);
}
__device__ __forceinline__ f16x2 bch(unsigned u) {
    return __builtin_bit_cast(f16x2, u);
}

#if __has_builtin(__builtin_amdgcn_fdot2)
__device__ __forceinline__ float fdot2(f16x2 a, f16x2 b, float c) {
    return __builtin_amdgcn_fdot2(a, b, c, false);
}
#else
__device__ __forceinline__ float fdot2(f16x2 a, f16x2 b, float c) {
    return c + (float)a.x * (float)b.x + (float)a.y * (float)b.y;
}
#endif

#if __has_builtin(__builtin_amdgcn_exp2f)
__device__ __forceinline__ float fexp2(float x) { return __builtin_amdgcn_exp2f(x); }
#else
__device__ __forceinline__ float fexp2(float x) { return exp2f(x); }
#endif

// d += broadcast(lo(w)) * x   — px0's weight from the paired word
__device__ __forceinline__ void pkfma_lo(f16x2& d, f16x2 w, f16x2 x) {
    asm("v_pk_fma_f16 %0, %1, %2, %0 op_sel:[0,0,0] op_sel_hi:[0,1,1]"
        : "+v"(d) : "v"(w), "v"(x));
}
// d += broadcast(hi(w)) * x   — px1's weight
__device__ __forceinline__ void pkfma_hi(f16x2& d, f16x2 w, f16x2 x) {
    asm("v_pk_fma_f16 %0, %1, %2, %0 op_sel:[1,0,0] op_sel_hi:[1,1,1]"
        : "+v"(d) : "v"(w), "v"(x));
}

// barrier WITHOUT vmcnt drain (global loads/stores stay in flight)
#define BAR() asm volatile("s_waitcnt lgkmcnt(0)\n\ts_barrier" ::: "memory")

// ---- issue group g's loads: 4 channels (rows A..D) per task ----
#define ISSUE_IN(g) do {                                                    \
    _Pragma("unroll")                                                       \
    for (int j = 0; j < 2; ++j) {                                           \
        iA[j] = make_float4(0.f, 0.f, 0.f, 0.f);                            \
        iB[j] = iA[j]; iC[j] = iA[j]; iD[j] = iA[j];                        \
        if (tv[j]) {                                                        \
            const float* p = inb + (size_t)((g) * 8 + 4 * tcpp[j]) * HWp    \
                             + toff[j];                                     \
            iA[j] = *(const float4*)p;                                      \
            iB[j] = *(const float4*)(p + HWp);                              \
            iC[j] = *(const float4*)(p + 2 * HWp);                          \
            iD[j] = *(const float4*)(p + 3 * HWp);                          \
        }                                                                   \
    }                                                                       \
} while (0)

// ---- pack + b64-write staged registers to dtu[g] ----
#define WRITE_IN(g) do {                                                    \
    _Pragma("unroll")                                                       \
    for (int j = 0; j < 2; ++j) {                                           \
        if (tok[j]) {                                                       \
            unsigned* bp = &dtu[(g)][ts0[j] * 4 + tcpp[j] * 2];             \
            *(uint2*)bp = make_uint2(pk(iA[j].y, iB[j].y),                  \
                                     pk(iC[j].y, iD[j].y));                 \
            *(uint2*)(bp + PAIRS * 4) = make_uint2(pk(iA[j].z, iB[j].z),    \
                                                   pk(iC[j].z, iD[j].z));   \
            if (!tq0[j])                                                    \
                *(uint2*)(bp + (PAIRS - 1) * 4) =                           \
                    make_uint2(pk(iA[j].x, iB[j].x), pk(iC[j].x, iD[j].x)); \
            if (!tq9[j])                                                    \
                *(uint2*)(bp + 4) =                                         \
                    make_uint2(pk(iA[j].w, iB[j].w), pk(iC[j].w, iD[j].w)); \
        }                                                                   \
    }                                                                       \
} while (0)

// ---- apply group g for BOTH pixels: 8 site-reads/row serve 2 px ----
#define APPLY(g) do {                                                       \
    const uint4* dg = (const uint4*)&dtu[(g)][0];                           \
    float acc0[8], acc1[8];                                                 \
    _Pragma("unroll") for (int c = 0; c < 8; ++c) { acc0[c] = 0.f; acc1[c] = 0.f; } \
    f16x2 A0 = (f16x2)0, A1 = (f16x2)0, A2 = (f16x2)0, A3 = (f16x2)0;       \
    f16x2 B0 = (f16x2)0, B1 = (f16x2)0, B2 = (f16x2)0, B3 = (f16x2)0;       \
    _Pragma("unroll")                                                       \
    for (int i = 0; i < KS; ++i) {                                          \
        const int rb = (ty + i) * 2 * PAIRS;                                \
        uint4 rq[8];                                                        \
        _Pragma("unroll")                                                   \
        for (int m = 0; m < 8; ++m) rq[m] = dg[rb + colAdd8[m]];            \
        _Pragma("unroll")                                                   \
        for (int k = 0; k < KS; ++k) {                                      \
            f16x2 wh = bch(wkp[i * KS + k]);                                \
            pkfma_lo(A0, wh, bch(rq[k].x));                                 \
            pkfma_lo(A1, wh, bch(rq[k].y));                                 \
            pkfma_lo(A2, wh, bch(rq[k].z));                                 \
            pkfma_lo(A3, wh, bch(rq[k].w));                                 \
            pkfma_hi(B0, wh, bch(rq[k + 1].x));                             \
            pkfma_hi(B1, wh, bch(rq[k + 1].y));                             \
            pkfma_hi(B2, wh, bch(rq[k + 1].z));                             \
            pkfma_hi(B3, wh, bch(rq[k + 1].w));                             \
        }                                                                   \
        if (i == 3) {   /* bound fp16 chain at 28 taps (R14-proven) */      \
            acc0[0] += (float)A0.x; acc0[1] += (float)A0.y;                 \
            acc0[2] += (float)A1.x; acc0[3] += (float)A1.y;                 \
            acc0[4] += (float)A2.x; acc0[5] += (float)A2.y;                 \
            acc0[6] += (float)A3.x; acc0[7] += (float)A3.y;                 \
            acc1[0] += (float)B0.x; acc1[1] += (float)B0.y;                 \
            acc1[2] += (float)B1.x; acc1[3] += (float)B1.y;                 \
            acc1[4] += (float)B2.x; acc1[5] += (float)B2.y;                 \
            acc1[6] += (float)B3.x; acc1[7] += (float)B3.y;                 \
            A0 = (f16x2)0; A1 = (f16x2)0; A2 = (f16x2)0; A3 = (f16x2)0;     \
            B0 = (f16x2)0; B1 = (f16x2)0; B2 = (f16x2)0; B3 = (f16x2)0;     \
        }                                                                   \
    }                                                                       \
    acc0[0] += (float)A0.x; acc0[1] += (float)A0.y;                         \
    acc0[2] += (float)A1.x; acc0[3] += (float)A1.y;                         \
    acc0[4] += (float)A2.x; acc0[5] += (float)A2.y;                         \
    acc0[6] += (float)A3.x; acc0[7] += (float)A3.y;                         \
    acc1[0] += (float)B0.x; acc1[1] += (float)B0.y;                         \
    acc1[2] += (float)B1.x; acc1[3] += (float)B1.y;                         \
    acc1[4] += (float)B2.x; acc1[5] += (float)B2.y;                         \
    acc1[6] += (float)B3.x; acc1[7] += (float)B3.y;                         \
    float* ob = out + ((size_t)b * 32 + (g) * 8) * HWp                      \
                + (size_t)Yo * W + Xo;                                      \
    _Pragma("unroll")                                                       \
    for (int c = 0; c < 8; ++c) {                                           \
        float2 s;                                                           \
        s.x = acc0[c] * inv0;                                               \
        s.y = acc1[c] * inv1;                                               \
        *(float2*)(ob + (size_t)c * HWp) = s;                               \
    }                                                                       \
} while (0)

__global__ __launch_bounds__(256)
void bilateral_kernel(const float* __restrict__ in,      // [B][32][H][W]
                      const float* __restrict__ guide,   // [B][3][H][W]
                      const float* __restrict__ sigma_p, // [1]
                      float* __restrict__ out)           // [B][32][H][W]
{
    // parity-split site: (row,col) -> (row*2 + (col&1))*PAIRS + (col>>1)
    __shared__ uint2 gt2[NSITE];                          // {pk(x~,y~), pk(z~,q~)}
    __shared__ __align__(16) unsigned dtu[4][NSITE * 4];  // 4 grp x 8ch fp16/site

    const int tid = threadIdx.x;
    const int tx  = tid & 15;            // x-PAIR index 0..15 (owns cols 2tx,2tx+1)
    const int ty  = tid >> 4;            // output row 0..15
    const int x0  = blockIdx.x * TW;
    const int y0  = blockIdx.y * TH;
    const int b   = blockIdx.z;

    const float* gb  = guide + (size_t)b * 3  * HWp;
    const float* inb = in    + (size_t)b * 32 * HWp;

    const float sigma = sigma_p[0];
    const float isig2 = 1.0f / (sigma * sigma);
    const float L2E   = 1.442695041f;          // log2(e)
    const float SQL   = 1.201122409f;          // sqrt(log2(e))
    float lnT2[KS];
#pragma unroll
    for (int i = 0; i < KS; ++i) {
        float r = (float)(i - RAD);
        lnT2[i] = -0.5f * r * r * isig2 * L2E;
    }

    // ---- hoisted staging task state: (row, quad q, ch-quad cpp) ----
    bool tok[2], tv[2], tq0[2], tq9[2];
    int  tcpp[2], toff[2], ts0[2];
#pragma unroll
    for (int j = 0; j < 2; ++j) {
        int t = tid + j * 256;
        tok[j] = t < NTASK2;
        int row = t / 20;
        int rem = t - row * 20;
        int q   = rem >> 1;
        tcpp[j] = rem & 1;
        int gy  = y0 - RAD + row;
        int gxb = x0 - 4 + 4 * q;
        tv[j]   = tok[j] && gy >= 0 && gy < H && gxb >= 0 && gxb < W;
        toff[j] = gy * W + gxb;
        ts0[j]  = row * 2 * PAIRS + 2 * q;
        tq0[j]  = (q == 0);
        tq9[j]  = (q == 9);
    }

    // ---- issue guide loads (220 quad-tasks, 1/thread), then g0 inputs ----
    float4 gX = make_float4(0.f, 0.f, 0.f, 0.f), gY = gX, gZ = gX;
    int grow = 0, gq = 0;
    if (tid < HR * 10) {
        grow = tid / 10; gq = tid - grow * 10;
        int gy  = y0 - RAD + grow;
        int gxb = x0 - 4 + 4 * gq;                // 4-aligned quad
        if (gy >= 0 && gy < H && gxb >= 0 && gxb < W) {
            const float* p = gb + gy * W + gxb;
            gX = *(const float4*)p;
            gY = *(const float4*)(p + HWp);
            gZ = *(const float4*)(p + 2 * HWp);
        }
    }
    float4 iA[2], iB[2], iC[2], iD[2];
    ISSUE_IN(0);                                  // g0 loads fly under guide+weights

    // ---- guide pack + LDS write ----
    if (tid < HR * 10) {
        int s0 = grow * 2 * PAIRS + 2 * gq;
        const float xs[4] = {gX.x, gX.y, gX.z, gX.w};
        const float ys[4] = {gY.x, gY.y, gY.z, gY.w};
        const float zs[4] = {gZ.x, gZ.y, gZ.z, gZ.w};
        const int   st[4] = {s0 + PAIRS - 1, s0, s0 + PAIRS, s0 + 1};
#pragma unroll
        for (int j = 0; j < 4; ++j) {
            if ((gq == 0 && j == 0) || (gq == 9 && j == 3)) continue;
            float ax = xs[j] * SQL, ay = ys[j] * SQL, az = zs[j] * SQL;
            float qv = -0.5f * (ax * ax + ay * ay + az * az);
            gt2[st[j]] = make_uint2(pk(ax, ay), pk(az, qv));
        }
    }
    BAR();                                        // gt2 ready (loads stay in flight)

    // ---- site offsets for cols 2tx+m, m=0..7 (hoisted) ----
    int colAdd8[8];
#pragma unroll
    for (int m = 0; m < 8; ++m)
        colAdd8[m] = (m & 1) * PAIRS + tx + (m >> 1);

    // ---- paired weights: wkp[i][k] = pk(w_px0, w_px1) ----
    const int cb = (ty + RAD) * 2 * PAIRS;
    uint2 c0r = gt2[cb + colAdd8[3]];             // px0 center: col 2tx+3
    uint2 c1r = gt2[cb + colAdd8[4]];             // px1 center: col 2tx+4
    const f16x2 cxy0 = bch(c0r.x), cxy1 = bch(c1r.x);
    f16x2 czq0 = bch(c0r.y), czq1 = bch(c1r.y);
    const float qc0 = (float)czq0.y, qc1 = (float)czq1.y;
    f16x2 cz10, cz11;
    cz10.x = czq0.x; cz10.y = (_Float16)1.0f;
    cz11.x = czq1.x; cz11.y = (_Float16)1.0f;

    unsigned wkp[KS * KS];
    float ns0 = 0.f, ns1 = 0.f;
#pragma unroll
    for (int i = 0; i < KS; ++i) {
        const int rb = (ty + i) * 2 * PAIRS;
        uint2 gq2[8];
#pragma unroll
        for (int m = 0; m < 8; ++m) gq2[m] = gt2[rb + colAdd8[m]];
        const float Qi0 = lnT2[i] + qc0;
        const float Qi1 = lnT2[i] + qc1;
#pragma unroll
        for (int k = 0; k < KS; ++k) {
            float e0 = fdot2(bch(gq2[k].x), cxy0,
                             fdot2(bch(gq2[k].y), cz10, Qi0 + lnT2[k]));
            float w0 = fexp2(e0);
            ns0 += w0;
            float e1 = fdot2(bch(gq2[k + 1].x), cxy1,
                             fdot2(bch(gq2[k + 1].y), cz11, Qi1 + lnT2[k]));
            float w1 = fexp2(e1);
            ns1 += w1;
            wkp[i * KS + k] = pk(w0, w1);
        }
    }
    const float inv0 = 1.f / ns0, inv1 = 1.f / ns1;   // >= ~1, never 0
    const int Xo = x0 + 2 * tx, Yo = y0 + ty;

    // ---- pipeline: write g, issue g+1 (flies across BAR), barrier, apply g ----
    WRITE_IN(0);
    ISSUE_IN(1);
    BAR();                        // dtu[0] ready; g1 loads + stores keep flying
    APPLY(0);
    WRITE_IN(1);
    ISSUE_IN(2);
    BAR();                        // dtu[1] ready
    APPLY(1);
    WRITE_IN(2);
    ISSUE_IN(3);
    BAR();                        // dtu[2] ready
    APPLY(2);
    WRITE_IN(3);
    BAR();                        // dtu[3] ready
    APPLY(3);
}

extern "C" void kernel_launch(void* const* d_in, const int* in_sizes, int n_in,
                              void* d_out, int out_size, void* d_ws, size_t ws_size,
                              hipStream_t stream) {
    const float* in    = (const float*)d_in[0];
    const float* guide = (const float*)d_in[1];
    const float* sigma = (const float*)d_in[2];
    float* out = (float*)d_out;
    dim3 grid(W / TW, H / TH, 2);   // 8 x 16 x 2 = 256 blocks, 1 per CU
    bilateral_kernel<<<grid, dim3(256), 0, stream>>>(in, guide, sigma, out);
}

// Round 26
// 19.681 us; speedup vs baseline: 1.0222x; 1.0222x over previous
//
#include <hip/hip_runtime.h>

#define KS    7
#define RAD   3
#define TW    32            // tile width (output px)
#define TH    8             // tile height (2 independent blocks/CU)
#define HR    14            // halo rows = TH + 2*RAD
#define PAIRS 21            // col-pairs per parity row (19 needed, +2 pad)
#define NSITE (HR*2*PAIRS)  // 588 sites
#define H     256
#define W     256
#define HWp   (H*W)
#define NTASK2 (HR*10*2)    // 280 staging tasks/group: (row, quad, ch-quad)

typedef __fp16    h2raw __attribute__((ext_vector_type(2)));
typedef _Float16  f16x2 __attribute__((ext_vector_type(2)));

__device__ __forceinline__ unsigned pk(float a, float b) {
    h2raw h = __builtin_amdgcn_cvt_pkrtz(a, b);
    return __builtin_bit_cast(unsigned, h);
}
__device__ __forceinline__ f16x2 bch(unsigned u) {
    return __builtin_bit_cast(f16x2, u);
}

#if __has_builtin(__builtin_amdgcn_fdot2)
__device__ __forceinline__ float fdot2(f16x2 a, f16x2 b, float c) {
    return __builtin_amdgcn_fdot2(a, b, c, false);
}
#else
__device__ __forceinline__ float fdot2(f16x2 a, f16x2 b, float c) {
    return c + (float)a.x * (float)b.x + (float)a.y * (float)b.y;
}
#endif

#if __has_builtin(__builtin_amdgcn_exp2f)
__device__ __forceinline__ float fexp2(float x) { return __builtin_amdgcn_exp2f(x); }
#else
__device__ __forceinline__ float fexp2(float x) { return exp2f(x); }
#endif

// guaranteed packed fma: d = a*b + d
__device__ __forceinline__ void pkfma(f16x2& d, f16x2 a, f16x2 b) {
    asm("v_pk_fma_f16 %0, %1, %2, %0" : "+v"(d) : "v"(a), "v"(b));
}

// barrier WITHOUT vmcnt drain (global loads/stores stay in flight)
#define BAR() asm volatile("s_waitcnt lgkmcnt(0)\n\ts_barrier" ::: "memory")

// ---- issue group g's loads: 4 channels (rows A..D) per task ----
#define ISSUE_IN(g) do {                                                    \
    _Pragma("unroll")                                                       \
    for (int j = 0; j < 2; ++j) {                                           \
        iA[j] = make_float4(0.f, 0.f, 0.f, 0.f);                            \
        iB[j] = iA[j]; iC[j] = iA[j]; iD[j] = iA[j];                        \
        if (tv[j]) {                                                        \
            const float* p = inb + (size_t)((g) * 8 + 4 * tcpp[j]) * HWp    \
                             + toff[j];                                     \
            iA[j] = *(const float4*)p;                                      \
            iB[j] = *(const float4*)(p + HWp);                              \
            iC[j] = *(const float4*)(p + 2 * HWp);                          \
            iD[j] = *(const float4*)(p + 3 * HWp);                          \
        }                                                                   \
    }                                                                       \
} while (0)

// ---- pack + b64-write staged registers to dtu[g] (words cpp*2, cpp*2+1) ----
#define WRITE_IN(g) do {                                                    \
    _Pragma("unroll")                                                       \
    for (int j = 0; j < 2; ++j) {                                           \
        if (tok[j]) {                                                       \
            unsigned* bp = &dtu[(g)][ts0[j] * 4 + tcpp[j] * 2];             \
            *(uint2*)bp = make_uint2(pk(iA[j].y, iB[j].y),                  \
                                     pk(iC[j].y, iD[j].y));                 \
            *(uint2*)(bp + PAIRS * 4) = make_uint2(pk(iA[j].z, iB[j].z),    \
                                                   pk(iC[j].z, iD[j].z));   \
            if (!tq0[j])                                                    \
                *(uint2*)(bp + (PAIRS - 1) * 4) =                           \
                    make_uint2(pk(iA[j].x, iB[j].x), pk(iC[j].x, iD[j].x)); \
            if (!tq9[j])                                                    \
                *(uint2*)(bp + 4) =                                         \
                    make_uint2(pk(iA[j].w, iB[j].w), pk(iC[j].w, iD[j].w)); \
        }                                                                   \
    }                                                                       \
} while (0)

// ---- apply group g: packed fma core, fp16 chains flushed at i==3 and end ----
#define APPLY(g) do {                                                       \
    const uint4* dg = (const uint4*)&dtu[(g)][0];                           \
    float acc[8];                                                           \
    _Pragma("unroll") for (int c = 0; c < 8; ++c) acc[c] = 0.f;             \
    f16x2 A0 = (f16x2)0, A1 = (f16x2)0, A2 = (f16x2)0, A3 = (f16x2)0;       \
    _Pragma("unroll")                                                       \
    for (int i = 0; i < KS; ++i) {                                          \
        const int rb = (ty + i) * 2 * PAIRS;                                \
        uint4 rq[KS];                                                       \
        _Pragma("unroll")                                                   \
        for (int k = 0; k < KS; ++k) rq[k] = dg[rb + colAdd[k]];            \
        _Pragma("unroll")                                                   \
        for (int k = 0; k < KS; ++k) {                                      \
            f16x2 wh = bch(wkp[i * KS + k]);                                \
            pkfma(A0, wh, bch(rq[k].x));                                    \
            pkfma(A1, wh, bch(rq[k].y));                                    \
            pkfma(A2, wh, bch(rq[k].z));                                    \
            pkfma(A3, wh, bch(rq[k].w));                                    \
        }                                                                   \
        if (i == 3) {   /* bound fp16 chain at 28 taps (R14-proven) */      \
            acc[0] += (float)A0.x; acc[1] += (float)A0.y;                   \
            acc[2] += (float)A1.x; acc[3] += (float)A1.y;                   \
            acc[4] += (float)A2.x; acc[5] += (float)A2.y;                   \
            acc[6] += (float)A3.x; acc[7] += (float)A3.y;                   \
            A0 = (f16x2)0; A1 = (f16x2)0; A2 = (f16x2)0; A3 = (f16x2)0;     \
        }                                                                   \
    }                                                                       \
    acc[0] += (float)A0.x; acc[1] += (float)A0.y;                           \
    acc[2] += (float)A1.x; acc[3] += (float)A1.y;                           \
    acc[4] += (float)A2.x; acc[5] += (float)A2.y;                           \
    acc[6] += (float)A3.x; acc[7] += (float)A3.y;                           \
    float* ob = out + ((size_t)b * 32 + (g) * 8) * HWp                      \
                + (size_t)Yo * W + Xo;                                      \
    _Pragma("unroll")                                                       \
    for (int c = 0; c < 8; ++c) ob[(size_t)c * HWp] = acc[c] * inv;         \
} while (0)

__global__ __launch_bounds__(256)
void bilateral_kernel(const float* __restrict__ in,      // [B][32][H][W]
                      const float* __restrict__ guide,   // [B][3][H][W]
                      const float* __restrict__ sigma_p, // [1]
                      float* __restrict__ out)           // [B][32][H][W]
{
    // parity-split site: (row,col) -> (row*2 + (col&1))*PAIRS + (col>>1)
    __shared__ uint2 gt2[NSITE];                          // {pk(x~,y~), pk(z~,q~)}
    __shared__ __align__(16) unsigned dtu[4][NSITE * 4];  // 4 grp x 8ch fp16/site

    const int tid = threadIdx.x;
    const int tx  = tid & 31;            // output col 0..31
    const int ty  = tid >> 5;            // output row 0..7
    const int x0  = blockIdx.x * TW;
    const int y0  = blockIdx.y * TH;
    const int b   = blockIdx.z;

    const float* gb  = guide + (size_t)b * 3  * HWp;
    const float* inb = in    + (size_t)b * 32 * HWp;

    const float sigma = sigma_p[0];
    const float isig2 = 1.0f / (sigma * sigma);
    const float L2E   = 1.442695041f;          // log2(e)
    const float SQL   = 1.201122409f;          // sqrt(log2(e))
    float lnT2[KS];
#pragma unroll
    for (int i = 0; i < KS; ++i) {
        float r = (float)(i - RAD);
        lnT2[i] = -0.5f * r * r * isig2 * L2E;
    }

    // ---- hoisted staging task state: (row, quad q, ch-quad cpp) ----
    bool tok[2], tv[2], tq0[2], tq9[2];
    int  tcpp[2], toff[2], ts0[2];
#pragma unroll
    for (int j = 0; j < 2; ++j) {
        int t = tid + j * 256;
        tok[j] = t < NTASK2;
        int row = t / 20;
        int rem = t - row * 20;
        int q   = rem >> 1;
        tcpp[j] = rem & 1;
        int gy  = y0 - RAD + row;
        int gxb = x0 - 4 + 4 * q;
        tv[j]   = tok[j] && gy >= 0 && gy < H && gxb >= 0 && gxb < W;
        toff[j] = gy * W + gxb;
        ts0[j]  = row * 2 * PAIRS + 2 * q;
        tq0[j]  = (q == 0);
        tq9[j]  = (q == 9);
    }

    // ---- issue guide loads (140 quad-tasks), then group-0 input loads ----
    float4 gX = make_float4(0.f, 0.f, 0.f, 0.f), gY = gX, gZ = gX;
    int grow = 0, gq = 0;
    if (tid < HR * 10) {
        grow = tid / 10; gq = tid - grow * 10;
        int gy  = y0 - RAD + grow;
        int gxb = x0 - 4 + 4 * gq;                // 4-aligned quad
        if (gy >= 0 && gy < H && gxb >= 0 && gxb < W) {
            const float* p = gb + gy * W + gxb;
            gX = *(const float4*)p;
            gY = *(const float4*)(p + HWp);
            gZ = *(const float4*)(p + 2 * HWp);
        }
    }
    float4 iA[2], iB[2], iC[2], iD[2];
    ISSUE_IN(0);                                  // g0 loads fly under guide+weights

    // ---- guide pack + LDS write ----
    if (tid < HR * 10) {
        int s0 = grow * 2 * PAIRS + 2 * gq;
        const float xs[4] = {gX.x, gX.y, gX.z, gX.w};
        const float ys[4] = {gY.x, gY.y, gY.z, gY.w};
        const float zs[4] = {gZ.x, gZ.y, gZ.z, gZ.w};
        const int   st[4] = {s0 + PAIRS - 1, s0, s0 + PAIRS, s0 + 1};
#pragma unroll
        for (int j = 0; j < 4; ++j) {
            if ((gq == 0 && j == 0) || (gq == 9 && j == 3)) continue;
            float ax = xs[j] * SQL, ay = ys[j] * SQL, az = zs[j] * SQL;
            float qv = -0.5f * (ax * ax + ay * ay + az * az);
            gt2[st[j]] = make_uint2(pk(ax, ay), pk(az, qv));
        }
    }
    BAR();                                        // gt2 ready (loads stay in flight)

    // ---- per-column site offsets (hoisted) ----
    int colAdd[KS];
#pragma unroll
    for (int k = 0; k < KS; ++k) {
        int col = tx + k;
        colAdd[k] = (col & 1) * PAIRS + (col >> 1);
    }

    // ---- weights (g0 loads in flight underneath) ----
    const int ccol = tx + RAD;
    uint2 cr = gt2[(ty + RAD) * 2 * PAIRS + (ccol & 1) * PAIRS + (ccol >> 1)];
    const f16x2 cxy = bch(cr.x);
    f16x2 czq = bch(cr.y);
    const float qc = (float)czq.y;
    f16x2 cz1;
    cz1.x = czq.x; cz1.y = (_Float16)1.0f;

    unsigned wkp[KS * KS];
    float nsum = 0.f;
#pragma unroll
    for (int i = 0; i < KS; ++i) {
        const int rb = (ty + i) * 2 * PAIRS;
        const float Qi = lnT2[i] + qc;
#pragma unroll
        for (int k = 0; k < KS; ++k) {
            uint2 g = gt2[rb + colAdd[k]];
            float e = fdot2(bch(g.x), cxy, fdot2(bch(g.y), cz1, Qi + lnT2[k]));
            float w = fexp2(e);
            nsum += w;
            wkp[i * KS + k] = pk(w, w);
        }
    }
    const float inv = 1.f / nsum;   // >= center weight ~= 1, never 0
    const int Xo = x0 + tx, Yo = y0 + ty;

    // ---- pipeline: write g, issue g+1 (flies across BAR), barrier, apply g ----
    WRITE_IN(0);
    ISSUE_IN(1);
    BAR();                        // dtu[0] ready; g1 loads + stores keep flying
    APPLY(0);
    WRITE_IN(1);
    ISSUE_IN(2);
    BAR();                        // dtu[1] ready
    APPLY(1);
    WRITE_IN(2);
    ISSUE_IN(3);
    BAR();                        // dtu[2] ready
    APPLY(2);
    WRITE_IN(3);
    BAR();                        // dtu[3] ready
    APPLY(3);
}

extern "C" void kernel_launch(void* const* d_in, const int* in_sizes, int n_in,
                              void* d_out, int out_size, void* d_ws, size_t ws_size,
                              hipStream_t stream) {
    const float* in    = (const float*)d_in[0];
    const float* guide = (const float*)d_in[1];
    const float* sigma = (const float*)d_in[2];
    float* out = (float*)d_out;
    dim3 grid(W / TW, H / TH, 2);   // 8 x 32 x 2 = 512 blocks, 2 per CU
    bilateral_kernel<<<grid, dim3(256), 0, stream>>>(in, guide, sigma, out);
}